// Round 2
// baseline (150.328 us; speedup 1.0000x reference)
//
#include <hip/hip_runtime.h>

#define TILE_W 64
#define TILE_H 4
#define HALO   2
#define LW     (TILE_W + 2*HALO)   // 68
#define LH     (TILE_H + 2*HALO)   // 8
#define IMG    512

// reflect index for np.pad(..., mode='reflect') with pad=2:
// g in [-2, 513] -> {2,1,0..511,510,509}
__device__ __forceinline__ int reflect_idx(int g) {
    int a = abs(g);
    return min(a, 2 * IMG - 2 - a);
}

// Scale so that exp(-50*d^2) == exp2(-(q_t - q_c)^2) with q = p*KS.
// KS = sqrt(50/ln2) = sqrt(72.13475204) = 8.4932184
#define KS      8.4932184f
#define INV_KS  0.11774083f
#define L2E_HLF 0.72134752f   // 0.5/ln2 (for spatial log2-weights)

__global__ __launch_bounds__(256) void bilateral_kernel(
    const float* __restrict__ img, float* __restrict__ out, int planes)
{
    __shared__ float q[LH][LW];

    const int plane = blockIdx.z;
    const int x0 = blockIdx.x * TILE_W;
    const int y0 = blockIdx.y * TILE_H;
    const float* __restrict__ src = img + (size_t)plane * (IMG * IMG);

    const int tid = threadIdx.x + threadIdx.y * TILE_W;  // block (64,4)

    // Stage LH*LW = 544 scaled elements with 256 threads.
    #pragma unroll
    for (int i = 0; i < 3; ++i) {
        int idx = tid + i * 256;
        if (idx < LH * LW) {
            int r = idx / LW;
            int c = idx - r * LW;
            int gr = reflect_idx(y0 - HALO + r);
            int gc = reflect_idx(x0 - HALO + c);
            q[r][c] = src[gr * IMG + gc] * KS;
        }
    }
    __syncthreads();

    const int tx = threadIdx.x, ty = threadIdx.y;
    const float qc = q[ty + HALO][tx + HALO];

    float wsum = 0.0f, acc = 0.0f;
    #pragma unroll
    for (int dy = 0; dy < 5; ++dy) {
        #pragma unroll
        for (int dx = 0; dx < 5; ++dx) {
            // compile-time spatial log2 weight
            const float ctap = -(float)((dx - 2) * (dx - 2) + (dy - 2) * (dy - 2)) * L2E_HLF;
            float qt  = q[ty + dy][tx + dx];
            float d   = qt - qc;
            float arg = __builtin_fmaf(-d, d, ctap);  // v_fma_f32 with neg mod
            float e   = __builtin_amdgcn_exp2f(arg);  // v_exp_f32
            wsum += e;
            acc = __builtin_fmaf(e, qt, acc);
        }
    }

    float inv = __builtin_amdgcn_rcpf(wsum + 1e-8f);
    out[(size_t)plane * (IMG * IMG) + (size_t)(y0 + ty) * IMG + (x0 + tx)] =
        acc * inv * INV_KS;
}

extern "C" void kernel_launch(void* const* d_in, const int* in_sizes, int n_in,
                              void* d_out, int out_size, void* d_ws, size_t ws_size,
                              hipStream_t stream) {
    const float* img = (const float*)d_in[0];
    float* out = (float*)d_out;
    int planes = in_sizes[0] / (IMG * IMG);  // 48
    dim3 grid(IMG / TILE_W, IMG / TILE_H, planes);
    dim3 block(TILE_W, TILE_H, 1);
    bilateral_kernel<<<grid, block, 0, stream>>>(img, out, planes);
}

// Round 3
// 149.614 us; speedup vs baseline: 1.0048x; 1.0048x over previous
//
#include <hip/hip_runtime.h>

#define IMG  512
#define TW   64
#define TH   16
#define RPT  4            // rows (pixels) per thread
#define HALO 2
#define LW   (TW + 2*HALO)   // 68
#define LH   (TH + 2*HALO)   // 20

typedef float v2f __attribute__((ext_vector_type(2)));

// reflect index for np.pad(..., mode='reflect') with pad=2
__device__ __forceinline__ int reflect_idx(int g) {
    int a = abs(g);
    return min(a, 2 * IMG - 2 - a);
}

// q = p * KS so that exp(-50 d^2) == exp2(-(dq)^2); KS = sqrt(50/ln2)
#define KS      8.4932184f
#define INV_KS  0.11774083f
#define L2E_HLF 0.72134752f   // 0.5/ln2

__global__ __launch_bounds__(256) void bilateral_kernel(
    const float* __restrict__ img, float* __restrict__ out)
{
    __shared__ float q[LH][LW];

    const int plane = blockIdx.z;
    const int x0 = blockIdx.x * TW;
    const int y0 = blockIdx.y * TH;
    const float* __restrict__ src = img + (size_t)plane * (IMG * IMG);

    const int tid = threadIdx.x + threadIdx.y * 64;   // block (64,4)

    // Stage LH*LW = 1360 scaled elements with 256 threads (6 passes).
    #pragma unroll
    for (int i = 0; i < 6; ++i) {
        int idx = tid + i * 256;
        if (idx < LH * LW) {
            int r = idx / LW;
            int c = idx - r * LW;
            q[r][c] = src[reflect_idx(y0 - HALO + r) * IMG + reflect_idx(x0 - HALO + c)] * KS;
        }
    }
    __syncthreads();

    const int tx = threadIdx.x;
    const int ry = threadIdx.y * RPT;   // first of this thread's 4 rows in tile

    // Batched LDS -> register window: 8 rows x 5 cols
    float w[RPT + 4][5];
    #pragma unroll
    for (int r = 0; r < RPT + 4; ++r)
        #pragma unroll
        for (int c = 0; c < 5; ++c)
            w[r][c] = q[ry + r][tx + c];

    float res[RPT];
    // two packed pixel-pairs: rows (p, p+1)
    #pragma unroll
    for (int p = 0; p < RPT; p += 2) {
        v2f qc;
        qc.x = w[p + 2][2];
        qc.y = w[p + 3][2];
        v2f wsum = {1.0f, 1.0f};   // center tap: e = 1
        v2f acc  = qc;             // center tap: e * qc

        #pragma unroll
        for (int dy = 0; dy < 5; ++dy) {
            #pragma unroll
            for (int dx = 0; dx < 5; ++dx) {
                if (dx == 2 && dy == 2) continue;   // center folded above
                const float ct = -(float)((dx-2)*(dx-2) + (dy-2)*(dy-2)) * L2E_HLF;
                const v2f ct2 = {ct, ct};
                v2f qt;
                qt.x = w[p + dy][dx];
                qt.y = w[p + 1 + dy][dx];
                v2f d   = qt - qc;                 // v_pk_add (neg)
                v2f arg = ct2 - d * d;             // contracts to v_pk_fma (neg)
                v2f e;
                e.x = __builtin_amdgcn_exp2f(arg.x);
                e.y = __builtin_amdgcn_exp2f(arg.y);
                wsum += e;                         // v_pk_add
                acc  += e * qt;                    // v_pk_fma
            }
        }
        res[p]     = acc.x * __builtin_amdgcn_rcpf(wsum.x + 1e-8f) * INV_KS;
        res[p + 1] = acc.y * __builtin_amdgcn_rcpf(wsum.y + 1e-8f) * INV_KS;
    }

    float* dst = out + (size_t)plane * (IMG * IMG)
                     + (size_t)(y0 + ry) * IMG + (x0 + tx);
    #pragma unroll
    for (int r = 0; r < RPT; ++r)
        dst[r * IMG] = res[r];
}

extern "C" void kernel_launch(void* const* d_in, const int* in_sizes, int n_in,
                              void* d_out, int out_size, void* d_ws, size_t ws_size,
                              hipStream_t stream) {
    const float* img = (const float*)d_in[0];
    float* out = (float*)d_out;
    int planes = in_sizes[0] / (IMG * IMG);  // 48
    dim3 grid(IMG / TW, IMG / TH, planes);
    dim3 block(64, 4, 1);
    bilateral_kernel<<<grid, block, 0, stream>>>(img, out);
}

// Round 4
// 131.107 us; speedup vs baseline: 1.1466x; 1.1412x over previous
//
#include <hip/hip_runtime.h>

#define IMG  512
#define TW   64            // tile width (px)
#define TH   8             // tile height
#define HALO 2
#define LWD  68            // data width
#define LW   69            // +1 pad: odd row stride -> row-pair reads split even/odd banks
#define LH   12

typedef float v2f __attribute__((ext_vector_type(2)));
typedef int   v2i __attribute__((ext_vector_type(2)));

// Pixel pre-scale: q = p * KS2 with KS2 = sqrt(50/ln2) * 2^11.5, so that
// d'^2 = (50/ln2)*d^2 * 2^23  -- intensity term directly in exponent-field units.
#define KS2      24598.990f
#define INV_KS2  4.0652061e-05f

// reflect index for np.pad(mode='reflect'), pad=2
__device__ __forceinline__ int reflect_idx(int g) {
    int a = abs(g);
    return min(a, 2 * IMG - 2 - a);
}

__global__ __launch_bounds__(256) void bilateral_kernel(
    const float* __restrict__ img, float* __restrict__ out)
{
    __shared__ float q[LH][LW];

    const int plane = blockIdx.z;
    const int x0 = blockIdx.x * TW;
    const int y0 = blockIdx.y * TH;
    const float* __restrict__ src = img + (size_t)plane * (IMG * IMG);

    const int tid = threadIdx.x + threadIdx.y * 32;   // block (32,8)

    // Stage LH x LWD = 816 scaled elements with 256 threads (4 passes).
    #pragma unroll
    for (int i = 0; i < 4; ++i) {
        int idx = tid + i * 256;
        if (idx < LH * LWD) {
            int r = idx / LWD;
            int c = idx - r * LWD;
            q[r][c] = src[reflect_idx(y0 - HALO + r) * IMG + reflect_idx(x0 - HALO + c)] * KS2;
        }
    }
    __syncthreads();

    const int tx = threadIdx.x, ty = threadIdx.y;
    const float* bp = &q[ty][2 * tx];   // top-left of this thread's 5x6 window

    v2f qc;
    qc.x = bp[2 * LW + 2];
    qc.y = bp[2 * LW + 3];

    v2f wsum = {1.0f, 1.0f};   // center tap: e = 1 exactly
    v2f acc  = qc;

    #pragma unroll
    for (int dy = 0; dy < 5; ++dy) {
        #pragma unroll
        for (int dx = 0; dx < 5; ++dx) {
            if (dx == 2 && dy == 2) continue;
            const int r2 = (dx - 2) * (dx - 2) + (dy - 2) * (dy - 2);
            // Ktap = 127*2^23 + 2^23 * log2(spatial) = bias - 2^23*(r2/2)/ln2
            const float Ktap = (float)(1065353216.0 - 6051101.63118 * (double)r2);

            const int off = dy * LW + dx;
            v2f qt;
            qt.x = bp[off];        // merges to ds_read2_b32
            qt.y = bp[off + 1];

            v2f d = qt - qc;                    // v_pk_add (neg)
            v2f t = Ktap - d * d;               // contracts to v_pk_fma
            v2i iv = __builtin_convertvector(t, v2i);   // 2x v_cvt_i32_f32 (trunc; t>0)
            v2f e = __builtin_bit_cast(v2f, iv);        // free reinterpret: e ~ 2^(arg)

            wsum += e;                          // v_pk_add
            acc  += e * qt;                     // v_pk_fma
        }
    }

    v2f res;
    res.x = acc.x * __builtin_amdgcn_rcpf(wsum.x) * INV_KS2;
    res.y = acc.y * __builtin_amdgcn_rcpf(wsum.y) * INV_KS2;

    float* dst = out + (size_t)plane * (IMG * IMG)
                     + (size_t)(y0 + ty) * IMG + (x0 + 2 * tx);
    *reinterpret_cast<v2f*>(dst) = res;   // 8B-aligned global_store_dwordx2
}

extern "C" void kernel_launch(void* const* d_in, const int* in_sizes, int n_in,
                              void* d_out, int out_size, void* d_ws, size_t ws_size,
                              hipStream_t stream) {
    const float* img = (const float*)d_in[0];
    float* out = (float*)d_out;
    int planes = in_sizes[0] / (IMG * IMG);  // 48
    dim3 grid(IMG / TW, IMG / TH, planes);
    dim3 block(32, 8, 1);
    bilateral_kernel<<<grid, block, 0, stream>>>(img, out);
}